// Round 8
// baseline (127.129 us; speedup 1.0000x reference)
//
#include <hip/hip_runtime.h>

#define CH_EPS 1e-6f
#define NPTS 8192
#define NB 4
#define NSEG 64
#define SEGSZ (NPTS / NSEG)        // 128 refs per segment
#define CHSZ 32                    // points per argmin chunk
#define NCH (SEGSZ / CHSZ)         // 4 chunks per segment
#define QPT 8                      // queries per thread
#define QCHUNK (256 * QPT)         // 2048 queries per block
#define NQ_TOT (2 * NB * NPTS)     // 65536 queries (dir, batch, point)
#define BIGF 3.0e38f
#define CHMASK 0xFFFFFF00u         // clear low 8 bits: stuff global chunk id

// Order-preserving float->uint bijection (uint min == float min).
__device__ __forceinline__ unsigned mono(float f) {
    unsigned b = __float_as_uint(f);
    return (b & 0x80000000u) ? ~b : (b | 0x80000000u);
}
__device__ __forceinline__ unsigned mono_inv(unsigned u) {
    return (u & 0x80000000u) ? (u & 0x7FFFFFFFu) : ~u;
}

// Phase 1: per-(query, segment) chunked min scan — NO LDS.
// Refs have no intra-wave reuse, so they stream straight from global via
// wave-uniform float4 loads (SMEM/VMEM pipe, L2-resident), freeing both the
// DS pipe and the barriers. t = 0.5*|y|^2 - x.y (same argmin as |x-y|^2);
// h computed on the fly, amortized over QPT queries. Once per 32-pt chunk
// the chunk min is folded (v_and_or_b32 + fmin) with its 8-bit global chunk
// id stuffed into low mantissa bits; cross-segment merge via one
// device-scope atomicMin per (query, segment) on the monotone-mapped key.
__global__ __launch_bounds__(256) void chamfer_partial(
    const float* __restrict__ xyz1, const float* __restrict__ xyz2,
    unsigned* __restrict__ part, float* __restrict__ out) {
    const int tid = threadIdx.x;
    const int chq = blockIdx.x;                 // 0..3 (2048-query chunks)
    const int seg = blockIdx.y;                 // 0..NSEG-1
    const int db = blockIdx.z;                  // 0..7
    const int dir = db >> 2, b = db & 3;

    // fold output zeroing into this kernel (finalize is a later dispatch)
    if (chq == 0 && seg == 0 && db == 0 && tid < 2) out[tid] = 0.0f;

    const float* Q = dir ? xyz2 : xyz1;
    // segment base: (b*NPTS + seg*SEGSZ)*3 floats = 16B-aligned (1536B step)
    const float4* Rg = (const float4*)((dir ? xyz1 : xyz2) +
                                       ((size_t)b * NPTS + seg * SEGSZ) * 3);

    float m0[QPT], m1[QPT], m2[QPT], bt[QPT];
    const int qi0 = chq * QCHUNK + tid;
#pragma unroll
    for (int q = 0; q < QPT; ++q) {
        const size_t off = ((size_t)b * NPTS + qi0 + q * 256) * 3;
        m0[q] = -Q[off]; m1[q] = -Q[off + 1]; m2[q] = -Q[off + 2];
        bt[q] = BIGF;
    }

    const unsigned gc0 = seg * NCH;             // global chunk id base (uniform)
#pragma unroll
    for (int cc = 0; cc < NCH; ++cc) {
        float cm[QPT];
#pragma unroll
        for (int q = 0; q < QPT; ++q) cm[q] = BIGF;
#pragma unroll 2
        for (int g = 0; g < CHSZ; g += 4) {
            // 4 refs = 48 B = 3 wave-uniform float4 loads
            const int k = ((cc * CHSZ + g) >> 2) * 3;
            const float4 f0 = Rg[k];
            const float4 f1 = Rg[k + 1];
            const float4 f2 = Rg[k + 2];
            // p0=(f0.x,f0.y,f0.z) p1=(f0.w,f1.x,f1.y)
            // p2=(f1.z,f1.w,f2.x) p3=(f2.y,f2.z,f2.w)
            const float h0 = 0.5f * fmaf(f0.x, f0.x, fmaf(f0.y, f0.y, f0.z * f0.z));
            const float h1 = 0.5f * fmaf(f0.w, f0.w, fmaf(f1.x, f1.x, f1.y * f1.y));
            const float h2 = 0.5f * fmaf(f1.z, f1.z, fmaf(f1.w, f1.w, f2.x * f2.x));
            const float h3 = 0.5f * fmaf(f2.y, f2.y, fmaf(f2.z, f2.z, f2.w * f2.w));
#pragma unroll
            for (int q = 0; q < QPT; ++q) {
                float t0 = fmaf(m0[q], f0.x, fmaf(m1[q], f0.y, fmaf(m2[q], f0.z, h0)));
                float t1 = fmaf(m0[q], f0.w, fmaf(m1[q], f1.x, fmaf(m2[q], f1.y, h1)));
                float t2 = fmaf(m0[q], f1.z, fmaf(m1[q], f1.w, fmaf(m2[q], f2.x, h2)));
                float t3 = fmaf(m0[q], f2.y, fmaf(m1[q], f2.z, fmaf(m2[q], f2.w, h3)));
                cm[q] = fminf(fminf(cm[q], t0), t1);   // -> v_min3_f32
                cm[q] = fminf(fminf(cm[q], t2), t3);   // -> v_min3_f32
            }
        }
        const unsigned gc = gc0 + cc;
#pragma unroll
        for (int q = 0; q < QPT; ++q) {
            // (bits & CHMASK) | gc  -> single v_and_or_b32
            float kk = __uint_as_float((__float_as_uint(cm[q]) & CHMASK) | gc);
            bt[q] = fminf(bt[q], kk);
        }
    }

    const int qbase = dir * (NB * NPTS) + b * NPTS + qi0;
#pragma unroll
    for (int q = 0; q < QPT; ++q)
        atomicMin(&part[qbase + q * 256], mono(bt[q]));
}

// Phase 2: one load per query (atomics already merged segments), decode the
// winning 32-point chunk, re-scan it exactly, distance + normal-consistency,
// block-reduce, atomicAdd.
__global__ __launch_bounds__(256) void finalize_kernel(
    const float* __restrict__ xyz1, const float* __restrict__ xyz2,
    const float* __restrict__ nxyz1, const float* __restrict__ nxyz2,
    const unsigned* __restrict__ part, float* __restrict__ out) {
    __shared__ float red[2][4];

    const int tid = threadIdx.x;
    const int q = blockIdx.x * 256 + tid;       // 0..65535
    const int dir = q >> 15;
    const int rem = q & 32767;
    const int b = rem >> 13;
    const int i = rem & 8191;

    const int c = (int)(mono_inv(part[q]) & 0xFFu);   // global 32-pt chunk

    const float* Q   = dir ? xyz2 : xyz1;
    const float* Rf  = dir ? xyz1 : xyz2;
    const float* NQp = dir ? nxyz2 : nxyz1;
    const float* NRp = dir ? nxyz1 : nxyz2;

    const size_t qoff = ((size_t)b * NPTS + i) * 3;
    const float x0 = Q[qoff], x1 = Q[qoff + 1], x2 = Q[qoff + 2];
    const float n0 = -x0, n1 = -x1, n2 = -x2;

    // re-scan winning chunk: exact argmin (strict <, ascending j)
    const float* Rs = Rf + ((size_t)b * NPTS + c * CHSZ) * 3;
    float btr = BIGF;
    int bj = 0;
    for (int j = 0; j < CHSZ; ++j) {
        float a = Rs[3 * j], cy = Rs[3 * j + 1], e = Rs[3 * j + 2];
        float h = 0.5f * fmaf(a, a, fmaf(cy, cy, e * e));
        float t = fmaf(n0, a, fmaf(n1, cy, fmaf(n2, e, h)));
        if (t < btr) { btr = t; bj = j; }
    }
    const int bi = c * CHSZ + bj;

    const size_t roff = ((size_t)b * NPTS + bi) * 3;
    const float y0 = Rf[roff], y1 = Rf[roff + 1], y2 = Rf[roff + 2];
    const float e0 = x0 - y0, e1 = x1 - y1, e2 = x2 - y2;
    float d = e0 * e0 + e1 * e1 + e2 * e2;      // exact squared distance

    const float a0 = NQp[qoff], a1 = NQp[qoff + 1], a2 = NQp[qoff + 2];
    const float c0 = NRp[roff], c1 = NRp[roff + 1], c2 = NRp[roff + 2];
    float na = sqrtf(a0 * a0 + a1 * a1 + a2 * a2);
    float nc = sqrtf(c0 * c0 + c1 * c1 + c2 * c2);
    float cs = (a0 * c0 + a1 * c1 + a2 * c2) /
               (fmaxf(na, CH_EPS) * fmaxf(nc, CH_EPS));
    float cn = 1.0f - fabsf(cs);

    for (int off = 32; off; off >>= 1) {
        d  += __shfl_down(d, off);
        cn += __shfl_down(cn, off);
    }
    const int lane = tid & 63, wv = tid >> 6;
    if (lane == 0) { red[0][wv] = d; red[1][wv] = cn; }
    __syncthreads();
    if (tid == 0) {
        float sd = red[0][0] + red[0][1] + red[0][2] + red[0][3];
        float sc = red[1][0] + red[1][1] + red[1][2] + red[1][3];
        const float inv = 1.0f / (float)(NB * NPTS);   // 1/32768
        atomicAdd(out + 0, sd * inv);
        atomicAdd(out + 1, sc * inv);
    }
}

extern "C" void kernel_launch(void* const* d_in, const int* in_sizes, int n_in,
                              void* d_out, int out_size, void* d_ws, size_t ws_size,
                              hipStream_t stream) {
    const float* xyz1  = (const float*)d_in[0];
    const float* xyz2  = (const float*)d_in[1];
    const float* nxyz1 = (const float*)d_in[2];
    const float* nxyz2 = (const float*)d_in[3];
    float* out = (float*)d_out;
    unsigned* part = (unsigned*)d_ws;           // 65536 * 4 B = 256 KB

    // init keys to +inf (all-ones = uint max)
    hipMemsetAsync(part, 0xFF, (size_t)NQ_TOT * sizeof(unsigned), stream);
    chamfer_partial<<<dim3(NPTS / QCHUNK, NSEG, 2 * NB), dim3(256), 0, stream>>>(
        xyz1, xyz2, part, out);
    finalize_kernel<<<dim3(NQ_TOT / 256), dim3(256), 0, stream>>>(
        xyz1, xyz2, nxyz1, nxyz2, part, out);
}

// Round 9
// 112.510 us; speedup vs baseline: 1.1299x; 1.1299x over previous
//
#include <hip/hip_runtime.h>

#define CH_EPS 1e-6f
#define NPTS 8192
#define NB 4
#define NSEG 64
#define SEGSZ (NPTS / NSEG)        // 128 refs per segment
#define CHSZ 16                    // points per argmin chunk
#define NCH (SEGSZ / CHSZ)         // 8 chunks per segment
#define QP 8                       // query PAIRS per thread (QPT = 16)
#define QCHUNK (256 * 2 * QP)      // 4096 queries per block
#define NQ_TOT (2 * NB * NPTS)     // 65536 queries (dir, batch, point)
#define BIGF 3.0e38f
#define CHMASK 0xFFFFFE00u         // clear low 9 bits: stuff global chunk id

typedef float v2f __attribute__((ext_vector_type(2)));

__device__ __forceinline__ v2f pkfma(v2f a, v2f b, v2f c) {
    return __builtin_elementwise_fma(a, b, c);
}
__device__ __forceinline__ v2f pkmin(v2f a, v2f b) {
    return __builtin_elementwise_min(a, b);
}
__device__ __forceinline__ v2f sp(float s) { return (v2f){s, s}; }

// Order-preserving float->uint bijection (uint min == float min).
__device__ __forceinline__ unsigned mono(float f) {
    unsigned b = __float_as_uint(f);
    return (b & 0x80000000u) ? ~b : (b | 0x80000000u);
}
__device__ __forceinline__ unsigned mono_inv(unsigned u) {
    return (u & 0x80000000u) ? (u & 0x7FFFFFFFu) : ~u;
}

// Phase 1: per-(query, segment) chunked min scan with TWO queries packed per
// v2f lane -> v_pk_fma_f32 (2x fp32 rate). t = 0.5*|y|^2 - x.y (same argmin
// as |x-y|^2). Refs staged in LDS (broadcast ds_read_b128, conflict-free);
// one read serves 16 queries. Once per 16-pt chunk the chunk min is folded
// with its 9-bit global chunk id stuffed into low mantissa bits; cross-
// segment merge via one device-scope atomicMin on the monotone-mapped key.
__global__ __launch_bounds__(256) void chamfer_partial(
    const float* __restrict__ xyz1, const float* __restrict__ xyz2,
    unsigned* __restrict__ part, float* __restrict__ out) {
    __shared__ float4 sY[SEGSZ];                // 2 KB

    const int tid = threadIdx.x;
    const int chq = blockIdx.x;                 // 0..1 (4096-query chunks)
    const int seg = blockIdx.y;                 // 0..NSEG-1
    const int db = blockIdx.z;                  // 0..7
    const int dir = db >> 2, b = db & 3;

    // fold output zeroing into this kernel (finalize is a later dispatch)
    if (chq == 0 && seg == 0 && db == 0 && tid < 2) out[tid] = 0.0f;

    const float* Q = dir ? xyz2 : xyz1;
    const float* R = (dir ? xyz1 : xyz2) + ((size_t)b * NPTS + seg * SEGSZ) * 3;

    // stage segment: (x, y, z, h = 0.5*|p|^2)
    if (tid < SEGSZ) {
        float a = R[3 * tid], c = R[3 * tid + 1], e = R[3 * tid + 2];
        sY[tid] = make_float4(a, c, e, 0.5f * fmaf(a, a, fmaf(c, c, e * e)));
    }

    // load 8 query pairs: pair k = queries qi0 + 2k*256 (.x), qi0+(2k+1)*256 (.y)
    v2f m0[QP], m1[QP], m2[QP], bt[QP];
    const int qi0 = chq * QCHUNK + tid;
#pragma unroll
    for (int k = 0; k < QP; ++k) {
        const size_t oa = ((size_t)b * NPTS + qi0 + (2 * k) * 256) * 3;
        const size_t ob = ((size_t)b * NPTS + qi0 + (2 * k + 1) * 256) * 3;
        m0[k] = (v2f){-Q[oa], -Q[ob]};
        m1[k] = (v2f){-Q[oa + 1], -Q[ob + 1]};
        m2[k] = (v2f){-Q[oa + 2], -Q[ob + 2]};
        bt[k] = sp(BIGF);
    }
    __syncthreads();

    const unsigned gc0 = seg * NCH;             // global chunk id base (uniform)
    for (int cc = 0; cc < NCH; ++cc) {
        v2f cm[QP];
#pragma unroll
        for (int k = 0; k < QP; ++k) cm[k] = sp(BIGF);
        const int jb = cc * CHSZ;
#pragma unroll
        for (int j = jb; j < jb + CHSZ; j += 4) {
            float4 y0 = sY[j];
            float4 y1 = sY[j + 1];
            float4 y2 = sY[j + 2];
            float4 y3 = sY[j + 3];
#pragma unroll
            for (int k = 0; k < QP; ++k) {
                v2f t0 = pkfma(m0[k], sp(y0.x), pkfma(m1[k], sp(y0.y), pkfma(m2[k], sp(y0.z), sp(y0.w))));
                v2f t1 = pkfma(m0[k], sp(y1.x), pkfma(m1[k], sp(y1.y), pkfma(m2[k], sp(y1.z), sp(y1.w))));
                v2f t2 = pkfma(m0[k], sp(y2.x), pkfma(m1[k], sp(y2.y), pkfma(m2[k], sp(y2.z), sp(y2.w))));
                v2f t3 = pkfma(m0[k], sp(y3.x), pkfma(m1[k], sp(y3.y), pkfma(m2[k], sp(y3.z), sp(y3.w))));
                cm[k] = pkmin(pkmin(cm[k], t0), t1);   // per-component v_min3
                cm[k] = pkmin(pkmin(cm[k], t2), t3);
            }
        }
        const unsigned gc = gc0 + cc;
#pragma unroll
        for (int k = 0; k < QP; ++k) {
            float kx = __uint_as_float((__float_as_uint(cm[k].x) & CHMASK) | gc);
            float ky = __uint_as_float((__float_as_uint(cm[k].y) & CHMASK) | gc);
            bt[k] = pkmin(bt[k], (v2f){kx, ky});
        }
    }

    const int qbase = dir * (NB * NPTS) + b * NPTS + qi0;
#pragma unroll
    for (int k = 0; k < QP; ++k) {
        atomicMin(&part[qbase + (2 * k) * 256], mono(bt[k].x));
        atomicMin(&part[qbase + (2 * k + 1) * 256], mono(bt[k].y));
    }
}

// Phase 2: one load per query (atomics already merged), decode the winning
// 16-point chunk, re-scan it exactly via float4 loads, distance +
// normal-consistency, block-reduce, atomicAdd.
__global__ __launch_bounds__(256) void finalize_kernel(
    const float* __restrict__ xyz1, const float* __restrict__ xyz2,
    const float* __restrict__ nxyz1, const float* __restrict__ nxyz2,
    const unsigned* __restrict__ part, float* __restrict__ out) {
    __shared__ float red[2][4];

    const int tid = threadIdx.x;
    const int q = blockIdx.x * 256 + tid;       // 0..65535
    const int dir = q >> 15;
    const int rem = q & 32767;
    const int b = rem >> 13;
    const int i = rem & 8191;

    const int c = (int)(mono_inv(part[q]) & 0x1FFu);   // global 16-pt chunk

    const float* Q   = dir ? xyz2 : xyz1;
    const float* Rf  = dir ? xyz1 : xyz2;
    const float* NQp = dir ? nxyz2 : nxyz1;
    const float* NRp = dir ? nxyz1 : nxyz2;

    const size_t qoff = ((size_t)b * NPTS + i) * 3;
    const float x0 = Q[qoff], x1 = Q[qoff + 1], x2 = Q[qoff + 2];
    const float n0 = -x0, n1 = -x1, n2 = -x2;

    // re-scan winning chunk (16 pts = 12 float4 loads; base is 192B-aligned)
    const float4* Rs = (const float4*)(Rf + ((size_t)b * NPTS + c * CHSZ) * 3);
    float btr = BIGF;
    int bj = 0;
#pragma unroll
    for (int g = 0; g < 4; ++g) {               // 4 groups of 4 points
        const float4 f0 = Rs[3 * g];
        const float4 f1 = Rs[3 * g + 1];
        const float4 f2 = Rs[3 * g + 2];
        const float px[4] = {f0.x, f0.w, f1.z, f2.y};
        const float py[4] = {f0.y, f1.x, f1.w, f2.z};
        const float pz[4] = {f0.z, f1.y, f2.x, f2.w};
#pragma unroll
        for (int u = 0; u < 4; ++u) {
            float h = 0.5f * fmaf(px[u], px[u], fmaf(py[u], py[u], pz[u] * pz[u]));
            float t = fmaf(n0, px[u], fmaf(n1, py[u], fmaf(n2, pz[u], h)));
            int j = 4 * g + u;
            if (t < btr) { btr = t; bj = j; }   // strict <, ascending j: exact
        }
    }
    const int bi = c * CHSZ + bj;

    const size_t roff = ((size_t)b * NPTS + bi) * 3;
    const float y0 = Rf[roff], y1 = Rf[roff + 1], y2 = Rf[roff + 2];
    const float e0 = x0 - y0, e1 = x1 - y1, e2 = x2 - y2;
    float d = e0 * e0 + e1 * e1 + e2 * e2;      // exact squared distance

    const float a0 = NQp[qoff], a1 = NQp[qoff + 1], a2 = NQp[qoff + 2];
    const float c0 = NRp[roff], c1 = NRp[roff + 1], c2 = NRp[roff + 2];
    float na = sqrtf(a0 * a0 + a1 * a1 + a2 * a2);
    float nc = sqrtf(c0 * c0 + c1 * c1 + c2 * c2);
    float cs = (a0 * c0 + a1 * c1 + a2 * c2) /
               (fmaxf(na, CH_EPS) * fmaxf(nc, CH_EPS));
    float cn = 1.0f - fabsf(cs);

    for (int off = 32; off; off >>= 1) {
        d  += __shfl_down(d, off);
        cn += __shfl_down(cn, off);
    }
    const int lane = tid & 63, wv = tid >> 6;
    if (lane == 0) { red[0][wv] = d; red[1][wv] = cn; }
    __syncthreads();
    if (tid == 0) {
        float sd = red[0][0] + red[0][1] + red[0][2] + red[0][3];
        float sc = red[1][0] + red[1][1] + red[1][2] + red[1][3];
        const float inv = 1.0f / (float)(NB * NPTS);   // 1/32768
        atomicAdd(out + 0, sd * inv);
        atomicAdd(out + 1, sc * inv);
    }
}

extern "C" void kernel_launch(void* const* d_in, const int* in_sizes, int n_in,
                              void* d_out, int out_size, void* d_ws, size_t ws_size,
                              hipStream_t stream) {
    const float* xyz1  = (const float*)d_in[0];
    const float* xyz2  = (const float*)d_in[1];
    const float* nxyz1 = (const float*)d_in[2];
    const float* nxyz2 = (const float*)d_in[3];
    float* out = (float*)d_out;
    unsigned* part = (unsigned*)d_ws;           // 65536 * 4 B = 256 KB

    // init keys to +inf (all-ones = uint max)
    hipMemsetAsync(part, 0xFF, (size_t)NQ_TOT * sizeof(unsigned), stream);
    chamfer_partial<<<dim3(NPTS / QCHUNK, NSEG, 2 * NB), dim3(256), 0, stream>>>(
        xyz1, xyz2, part, out);
    finalize_kernel<<<dim3(NQ_TOT / 256), dim3(256), 0, stream>>>(
        xyz1, xyz2, nxyz1, nxyz2, part, out);
}